// Round 3
// baseline (395.778 us; speedup 1.0000x reference)
//
#include <hip/hip_runtime.h>
#include <hip/hip_bf16.h>
#include <math.h>

// MultiHash R9: split the fused kernel into two dispatches to decouple the
// two regimes that were fighting over occupancy knobs:
//   encode  — 64 scattered 8B L2 table reads/lane. Latency-bound; wants max
//             waves, zero LDS, low VGPR. Now: no LDS, (256,4), feat -> d_ws
//             as hi/lo bf16 (128 MB). ~16 waves/CU vs ~10 fused.
//   mlp     — MFMA 3-layer. Layer-1 A-frags read DIRECTLY from global
//             (streaming), so the sF LDS region is gone: LDS 9216 B, live
//             set ~95 regs -> (64,4), 16 waves/CU, no spill.
// Cost: +256 MB HBM round-trip for feat (~40 us at 6.3 TB/s) — paid for by
// 4-5x latency hiding in encode and 1.6x occupancy in mlp.
// R8 post-mortem: spill fixed (WRITE 78->12 MB) but no pipe above 25% busy
// -> latency-bound; fused structure couples LDS-aliasing (needs +32 reg
// preload) against the 128-reg/4-wave budget. Split removes the coupling.
// Fallback: if ws_size < 28 KB + n*128 B, launch the R8 fused kernel.
// Encoding math / fragment layouts / epilogues unchanged (R6-validated,
// absmax 1.49e-8 vs 8.9e-8 threshold).

#define TBL_MASK 16383u
#define PRIME1   2654435761u

typedef __attribute__((ext_vector_type(8))) short short8;
typedef __attribute__((ext_vector_type(4))) float f32x4;
typedef __attribute__((ext_vector_type(4))) unsigned int uint4v;

struct ResArr { float r[16]; };

__device__ __forceinline__ unsigned short bf16rn(float f) {
    __hip_bfloat16 h = __float2bfloat16(f);   // RNE
    return __builtin_bit_cast(unsigned short, h);
}
__device__ __forceinline__ float bf16tof(unsigned short u) {
    unsigned int xx = ((unsigned int)u) << 16;
    return __builtin_bit_cast(float, xx);
}
__device__ __forceinline__ short8 ld8(const unsigned short* p) {
    return __builtin_bit_cast(short8, *(const uint4v*)p);
}

#define MFMA(a, b, c) __builtin_amdgcn_mfma_f32_16x16x32_bf16((a), (b), (c), 0, 0, 0)

// ---- workspace layout (ushort offsets), 16B-aligned blocks ----
#define W1H_OFF 0        // [64][32]
#define W1L_OFF 2048
#define W2H_OFF 4096     // [64][64]
#define W2L_OFF 8192
#define W3H_OFF 12288    // [16][64], rows 3..15 zero
#define W3L_OFF 13312
#define WS_USHORTS 14336 // 28672 B; feat array starts here (16B-aligned)
// feat layout: per sample, 64 ushorts: [0..31] = hi bf16 of k=0..31,
//              [32..63] = lo bf16. Row stride 128 B.

__global__ __launch_bounds__(256) void split_weights(
    const float* __restrict__ W1, const float* __restrict__ W2,
    const float* __restrict__ W3, unsigned short* __restrict__ ws)
{
    const int t = blockIdx.x * blockDim.x + threadIdx.x;
    const int stride = gridDim.x * blockDim.x;
    for (int i = t; i < 2048; i += stride) {
        const float v = W1[i];
        const unsigned short hb = bf16rn(v);
        ws[W1H_OFF + i] = hb;
        ws[W1L_OFF + i] = bf16rn(v - bf16tof(hb));
    }
    for (int i = t; i < 4096; i += stride) {
        const float v = W2[i];
        const unsigned short hb = bf16rn(v);
        ws[W2H_OFF + i] = hb;
        ws[W2L_OFF + i] = bf16rn(v - bf16tof(hb));
    }
    for (int i = t; i < 1024; i += stride) {
        const float v = (i < 192) ? W3[i] : 0.0f;   // W3 is [3][64]; pad to 16 rows
        const unsigned short hb = bf16rn(v);
        ws[W3H_OFF + i] = hb;
        ws[W3L_OFF + i] = bf16rn(v - bf16tof(hb));
    }
}

// ---------------- encode: hash-grid lookup -> feat (hi/lo bf16) ----------------
__global__ __launch_bounds__(256, 4) void mh_encode(
    const float* __restrict__ x,
    const float* __restrict__ tables,
    unsigned short* __restrict__ feat,
    ResArr res, int n)
{
    long s = (long)blockIdx.x * 256 + threadIdx.x;
    if (s >= (long)n) s = (long)n - 1;   // clamped lanes recompute row n-1 (benign)

    const float2 xv = reinterpret_cast<const float2*>(x)[s];
    const float2* __restrict__ tbl2 = reinterpret_cast<const float2*>(tables);

    unsigned int hiu[16], lou[16];       // static-indexed via full unroll (rule #20)

    #pragma unroll
    for (int l = 0; l < 16; ++l) {
        const float r  = res.r[l];
        const float sx = xv.x * r;
        const float sy = xv.y * r;
        const float gx = floorf(sx);
        const float gy = floorf(sy);
        const unsigned ux = (unsigned)(int)gx;
        const unsigned uy = (unsigned)(int)gy;
        const unsigned hy0 = uy * PRIME1;
        const unsigned hy1 = hy0 + PRIME1;
        const unsigned i00 = ( ux       ^ hy0) & TBL_MASK;
        const unsigned i10 = ((ux + 1u) ^ hy0) & TBL_MASK;
        const unsigned i01 = ( ux       ^ hy1) & TBL_MASK;
        const unsigned i11 = ((ux + 1u) ^ hy1) & TBL_MASK;
        const float2* tl = tbl2 + (l << 14);
        const float2 t00 = tl[i00];
        const float2 t10 = tl[i10];
        const float2 t01 = tl[i01];
        const float2 t11 = tl[i11];
        const float wx0 = 1.0f - fabsf(sx - gx);
        const float wx1 = 1.0f - fabsf(sx - (gx + 1.0f));
        const float wy0 = 1.0f - fabsf(sy - gy);
        const float wy1 = 1.0f - fabsf(sy - (gy + 1.0f));
        const float w00 = wx0 * wy0;
        const float w10 = wx1 * wy0;
        const float w01 = wx0 * wy1;
        const float w11 = wx1 * wy1;
        const float f0 = fmaf(w00, t00.x, fmaf(w10, t10.x, fmaf(w01, t01.x, w11 * t11.x)));
        const float f1 = fmaf(w00, t00.y, fmaf(w10, t10.y, fmaf(w01, t01.y, w11 * t11.y)));
        const unsigned short h0 = bf16rn(f0);
        const unsigned short h1e = bf16rn(f1);
        const unsigned short l0 = bf16rn(f0 - bf16tof(h0));
        const unsigned short l1 = bf16rn(f1 - bf16tof(h1e));
        hiu[l] = (unsigned)h0 | ((unsigned)h1e << 16);
        lou[l] = (unsigned)l0 | ((unsigned)l1 << 16);
    }

    // 8 x 16B stores; row = 128 B, 16B-aligned.
    uint4v* row = (uint4v*)(feat + (size_t)s * 64);
    #pragma unroll
    for (int c = 0; c < 4; ++c) {
        uint4v vh = { hiu[c*4+0], hiu[c*4+1], hiu[c*4+2], hiu[c*4+3] };
        row[c] = vh;
    }
    #pragma unroll
    for (int c = 0; c < 4; ++c) {
        uint4v vl = { lou[c*4+0], lou[c*4+1], lou[c*4+2], lou[c*4+3] };
        row[4 + c] = vl;
    }
}

// ---------------- mlp: 32 -> 64 -> 64 -> 3 over 64 samples/wave ----------------
__global__ __launch_bounds__(64, 4) void mh_mlp(
    const unsigned short* __restrict__ feat,
    const unsigned short* __restrict__ wsw,
    const float* __restrict__ b1,
    const float* __restrict__ b2,
    const float* __restrict__ b3,
    float* __restrict__ out, int n)
{
    // h1/h2 staging only: [32 rows][64 cols + 8 pad] bf16 hi + lo
    __shared__ __align__(16) unsigned short sAH[32 * 72];
    __shared__ __align__(16) unsigned short sAL[32 * 72];

    const int L  = threadIdx.x;
    const int ln = L & 15;
    const int q  = L >> 4;
    const long base = (long)blockIdx.x * 64;

    float b1v[4], b2v[4];
    #pragma unroll
    for (int nt = 0; nt < 4; ++nt) { b1v[nt] = b1[nt * 16 + ln]; b2v[nt] = b2[nt * 16 + ln]; }
    const float b3v = (ln < 3) ? b3[ln] : 0.0f;

    const f32x4 zero4 = {0.0f, 0.0f, 0.0f, 0.0f};

    for (int mh = 0; mh < 2; ++mh) {          // 32-sample halves
        // ---------------- layer 1 (A-frags straight from global) ----------------
        short8 a1h[2], a1l[2];
        #pragma unroll
        for (int mt = 0; mt < 2; ++mt) {
            long row = base + mh * 32 + mt * 16 + ln;
            if (row >= (long)n) row = (long)n - 1;   // clamp (loads only)
            const unsigned short* rp = feat + (size_t)row * 64;
            a1h[mt] = ld8(rp + q * 8);
            a1l[mt] = ld8(rp + 32 + q * 8);
        }
        f32x4 acc1[2][4];
        #pragma unroll
        for (int mt = 0; mt < 2; ++mt)
            #pragma unroll
            for (int nt = 0; nt < 4; ++nt) acc1[mt][nt] = zero4;

        #pragma unroll
        for (int nt = 0; nt < 4; ++nt) {
            const short8 bh = ld8(&wsw[W1H_OFF + (nt * 16 + ln) * 32 + q * 8]);
            const short8 bl = ld8(&wsw[W1L_OFF + (nt * 16 + ln) * 32 + q * 8]);
            #pragma unroll
            for (int mt = 0; mt < 2; ++mt) {
                f32x4 a = acc1[mt][nt];
                a = MFMA(a1l[mt], bh, a);
                a = MFMA(a1h[mt], bl, a);
                a = MFMA(a1h[mt], bh, a);
                acc1[mt][nt] = a;
            }
        }
        // epilogue: bias + relu + split -> sAH/sAL rows 0..31
        #pragma unroll
        for (int mt = 0; mt < 2; ++mt)
            #pragma unroll
            for (int nt = 0; nt < 4; ++nt) {
                const int col = nt * 16 + ln;
                #pragma unroll
                for (int r = 0; r < 4; ++r) {
                    float v = fmaxf(acc1[mt][nt][r] + b1v[nt], 0.0f);
                    const unsigned short hb = bf16rn(v);
                    const unsigned short lb = bf16rn(v - bf16tof(hb));
                    const int rl = mt * 16 + q * 4 + r;
                    sAH[rl * 72 + col] = hb;
                    sAL[rl * 72 + col] = lb;
                }
            }

        // ---------------- layer 2 ----------------
        short8 a2h[2][2], a2l[2][2];
        #pragma unroll
        for (int mt = 0; mt < 2; ++mt)
            #pragma unroll
            for (int ks = 0; ks < 2; ++ks) {
                const int row = mt * 16 + ln;
                a2h[mt][ks] = ld8(&sAH[row * 72 + ks * 32 + q * 8]);
                a2l[mt][ks] = ld8(&sAL[row * 72 + ks * 32 + q * 8]);
            }
        f32x4 acc2[2][4];
        #pragma unroll
        for (int mt = 0; mt < 2; ++mt)
            #pragma unroll
            for (int nt = 0; nt < 4; ++nt) acc2[mt][nt] = zero4;

        #pragma unroll
        for (int nt = 0; nt < 4; ++nt)
            #pragma unroll
            for (int ks = 0; ks < 2; ++ks) {
                const short8 bh = ld8(&wsw[W2H_OFF + (nt * 16 + ln) * 64 + ks * 32 + q * 8]);
                const short8 bl = ld8(&wsw[W2L_OFF + (nt * 16 + ln) * 64 + ks * 32 + q * 8]);
                #pragma unroll
                for (int mt = 0; mt < 2; ++mt) {
                    f32x4 a = acc2[mt][nt];
                    a = MFMA(a2l[mt][ks], bh, a);
                    a = MFMA(a2h[mt][ks], bl, a);
                    a = MFMA(a2h[mt][ks], bh, a);
                    acc2[mt][nt] = a;
                }
            }
        // epilogue -> overwrite sAH/sAL (same-wave DS ops retire in order;
        // A-frags above already read)
        #pragma unroll
        for (int mt = 0; mt < 2; ++mt)
            #pragma unroll
            for (int nt = 0; nt < 4; ++nt) {
                const int col = nt * 16 + ln;
                #pragma unroll
                for (int r = 0; r < 4; ++r) {
                    float v = fmaxf(acc2[mt][nt][r] + b2v[nt], 0.0f);
                    const unsigned short hb = bf16rn(v);
                    const unsigned short lb = bf16rn(v - bf16tof(hb));
                    const int rl = mt * 16 + q * 4 + r;
                    sAH[rl * 72 + col] = hb;
                    sAL[rl * 72 + col] = lb;
                }
            }

        // ---------------- layer 3 ----------------
        short8 a3h[2][2], a3l[2][2];
        #pragma unroll
        for (int mt = 0; mt < 2; ++mt)
            #pragma unroll
            for (int ks = 0; ks < 2; ++ks) {
                const int row = mt * 16 + ln;
                a3h[mt][ks] = ld8(&sAH[row * 72 + ks * 32 + q * 8]);
                a3l[mt][ks] = ld8(&sAL[row * 72 + ks * 32 + q * 8]);
            }
        f32x4 acc3[2] = {zero4, zero4};
        #pragma unroll
        for (int ks = 0; ks < 2; ++ks) {
            // W3 pre-padded to 16 rows (3..15 zero) -> no divergent mask
            const short8 bh = ld8(&wsw[W3H_OFF + ln * 64 + ks * 32 + q * 8]);
            const short8 bl = ld8(&wsw[W3L_OFF + ln * 64 + ks * 32 + q * 8]);
            #pragma unroll
            for (int mt = 0; mt < 2; ++mt) {
                f32x4 a = acc3[mt];
                a = MFMA(a3l[mt][ks], bh, a);
                a = MFMA(a3h[mt][ks], bl, a);
                a = MFMA(a3h[mt][ks], bh, a);
                acc3[mt] = a;
            }
        }
        // store: C col = ln (channel, <3), rows = samples
        if (ln < 3) {
            #pragma unroll
            for (int mt = 0; mt < 2; ++mt)
                #pragma unroll
                for (int r = 0; r < 4; ++r) {
                    const long sg = base + mh * 32 + mt * 16 + q * 4 + r;
                    if (sg < (long)n) out[sg * 3 + ln] = acc3[mt][r] + b3v;
                }
        }
    }
}

// ---------------- fused fallback (R8, unchanged) ----------------
__global__ __launch_bounds__(64, 3) void mh_mfma(
    const float* __restrict__ x,
    const float* __restrict__ tables,
    const unsigned short* __restrict__ wsw,
    const float* __restrict__ b1,
    const float* __restrict__ b2,
    const float* __restrict__ b3,
    float* __restrict__ out,
    ResArr res, int n)
{
    __shared__ __align__(16) unsigned short smem[5120];
    unsigned short* const sFH = smem;
    unsigned short* const sFL = smem + 2560;
    unsigned short* const sAH = smem;
    unsigned short* const sAL = smem + 2304;

    const int L  = threadIdx.x;
    const int ln = L & 15;
    const int q  = L >> 4;
    const long base = (long)blockIdx.x * 64;
    long s = base + L;
    if (s >= (long)n) s = (long)n - 1;

    const float2 xv = reinterpret_cast<const float2*>(x)[s];
    const float2* __restrict__ tbl2 = reinterpret_cast<const float2*>(tables);

    #pragma unroll 4
    for (int l = 0; l < 16; ++l) {
        const float r  = res.r[l];
        const float sx = xv.x * r;
        const float sy = xv.y * r;
        const float gx = floorf(sx);
        const float gy = floorf(sy);
        const unsigned ux = (unsigned)(int)gx;
        const unsigned uy = (unsigned)(int)gy;
        const unsigned hy0 = uy * PRIME1;
        const unsigned hy1 = hy0 + PRIME1;
        const unsigned i00 = ( ux       ^ hy0) & TBL_MASK;
        const unsigned i10 = ((ux + 1u) ^ hy0) & TBL_MASK;
        const unsigned i01 = ( ux       ^ hy1) & TBL_MASK;
        const unsigned i11 = ((ux + 1u) ^ hy1) & TBL_MASK;
        const float2* tl = tbl2 + (l << 14);
        const float2 t00 = tl[i00];
        const float2 t10 = tl[i10];
        const float2 t01 = tl[i01];
        const float2 t11 = tl[i11];
        const float wx0 = 1.0f - fabsf(sx - gx);
        const float wx1 = 1.0f - fabsf(sx - (gx + 1.0f));
        const float wy0 = 1.0f - fabsf(sy - gy);
        const float wy1 = 1.0f - fabsf(sy - (gy + 1.0f));
        const float w00 = wx0 * wy0;
        const float w10 = wx1 * wy0;
        const float w01 = wx0 * wy1;
        const float w11 = wx1 * wy1;
        const float f0 = fmaf(w00, t00.x, fmaf(w10, t10.x, fmaf(w01, t01.x, w11 * t11.x)));
        const float f1 = fmaf(w00, t00.y, fmaf(w10, t10.y, fmaf(w01, t01.y, w11 * t11.y)));
        const unsigned short h0 = bf16rn(f0);
        const unsigned short h1e = bf16rn(f1);
        const unsigned short l0 = bf16rn(f0 - bf16tof(h0));
        const unsigned short l1 = bf16rn(f1 - bf16tof(h1e));
        *(unsigned int*)&sFH[L * 40 + 2 * l] = (unsigned)h0 | ((unsigned)h1e << 16);
        *(unsigned int*)&sFL[L * 40 + 2 * l] = (unsigned)l0 | ((unsigned)l1 << 16);
    }

    short8 a1h[2][2], a1l[2][2];
    #pragma unroll
    for (int mh = 0; mh < 2; ++mh)
        #pragma unroll
        for (int mt = 0; mt < 2; ++mt) {
            const int row = mh * 32 + mt * 16 + ln;
            a1h[mh][mt] = ld8(&sFH[row * 40 + q * 8]);
            a1l[mh][mt] = ld8(&sFL[row * 40 + q * 8]);
        }

    float b1v[4], b2v[4];
    #pragma unroll
    for (int nt = 0; nt < 4; ++nt) { b1v[nt] = b1[nt * 16 + ln]; b2v[nt] = b2[nt * 16 + ln]; }
    const float b3v = (ln < 3) ? b3[ln] : 0.0f;

    const f32x4 zero4 = {0.0f, 0.0f, 0.0f, 0.0f};

    for (int mh = 0; mh < 2; ++mh) {
        f32x4 acc1[2][4];
        #pragma unroll
        for (int mt = 0; mt < 2; ++mt)
            #pragma unroll
            for (int nt = 0; nt < 4; ++nt) acc1[mt][nt] = zero4;

        #pragma unroll
        for (int nt = 0; nt < 4; ++nt) {
            const short8 bh = ld8(&wsw[W1H_OFF + (nt * 16 + ln) * 32 + q * 8]);
            const short8 bl = ld8(&wsw[W1L_OFF + (nt * 16 + ln) * 32 + q * 8]);
            #pragma unroll
            for (int mt = 0; mt < 2; ++mt) {
                f32x4 a = acc1[mt][nt];
                a = MFMA(a1l[mh][mt], bh, a);
                a = MFMA(a1h[mh][mt], bl, a);
                a = MFMA(a1h[mh][mt], bh, a);
                acc1[mt][nt] = a;
            }
        }
        #pragma unroll
        for (int mt = 0; mt < 2; ++mt)
            #pragma unroll
            for (int nt = 0; nt < 4; ++nt) {
                const int col = nt * 16 + ln;
                #pragma unroll
                for (int r = 0; r < 4; ++r) {
                    float v = fmaxf(acc1[mt][nt][r] + b1v[nt], 0.0f);
                    const unsigned short hb = bf16rn(v);
                    const unsigned short lb = bf16rn(v - bf16tof(hb));
                    const int rl = mt * 16 + q * 4 + r;
                    sAH[rl * 72 + col] = hb;
                    sAL[rl * 72 + col] = lb;
                }
            }

        short8 a2h[2][2], a2l[2][2];
        #pragma unroll
        for (int mt = 0; mt < 2; ++mt)
            #pragma unroll
            for (int ks = 0; ks < 2; ++ks) {
                const int row = mt * 16 + ln;
                a2h[mt][ks] = ld8(&sAH[row * 72 + ks * 32 + q * 8]);
                a2l[mt][ks] = ld8(&sAL[row * 72 + ks * 32 + q * 8]);
            }
        f32x4 acc2[2][4];
        #pragma unroll
        for (int mt = 0; mt < 2; ++mt)
            #pragma unroll
            for (int nt = 0; nt < 4; ++nt) acc2[mt][nt] = zero4;

        #pragma unroll
        for (int nt = 0; nt < 4; ++nt)
            #pragma unroll
            for (int ks = 0; ks < 2; ++ks) {
                const short8 bh = ld8(&wsw[W2H_OFF + (nt * 16 + ln) * 64 + ks * 32 + q * 8]);
                const short8 bl = ld8(&wsw[W2L_OFF + (nt * 16 + ln) * 64 + ks * 32 + q * 8]);
                #pragma unroll
                for (int mt = 0; mt < 2; ++mt) {
                    f32x4 a = acc2[mt][nt];
                    a = MFMA(a2l[mt][ks], bh, a);
                    a = MFMA(a2h[mt][ks], bl, a);
                    a = MFMA(a2h[mt][ks], bh, a);
                    acc2[mt][nt] = a;
                }
            }
        #pragma unroll
        for (int mt = 0; mt < 2; ++mt)
            #pragma unroll
            for (int nt = 0; nt < 4; ++nt) {
                const int col = nt * 16 + ln;
                #pragma unroll
                for (int r = 0; r < 4; ++r) {
                    float v = fmaxf(acc2[mt][nt][r] + b2v[nt], 0.0f);
                    const unsigned short hb = bf16rn(v);
                    const unsigned short lb = bf16rn(v - bf16tof(hb));
                    const int rl = mt * 16 + q * 4 + r;
                    sAH[rl * 72 + col] = hb;
                    sAL[rl * 72 + col] = lb;
                }
            }

        short8 a3h[2][2], a3l[2][2];
        #pragma unroll
        for (int mt = 0; mt < 2; ++mt)
            #pragma unroll
            for (int ks = 0; ks < 2; ++ks) {
                const int row = mt * 16 + ln;
                a3h[mt][ks] = ld8(&sAH[row * 72 + ks * 32 + q * 8]);
                a3l[mt][ks] = ld8(&sAL[row * 72 + ks * 32 + q * 8]);
            }
        f32x4 acc3[2] = {zero4, zero4};
        #pragma unroll
        for (int ks = 0; ks < 2; ++ks) {
            const short8 bh = ld8(&wsw[W3H_OFF + ln * 64 + ks * 32 + q * 8]);
            const short8 bl = ld8(&wsw[W3L_OFF + ln * 64 + ks * 32 + q * 8]);
            #pragma unroll
            for (int mt = 0; mt < 2; ++mt) {
                f32x4 a = acc3[mt];
                a = MFMA(a3l[mt][ks], bh, a);
                a = MFMA(a3h[mt][ks], bl, a);
                a = MFMA(a3h[mt][ks], bh, a);
                acc3[mt] = a;
            }
        }
        if (ln < 3) {
            #pragma unroll
            for (int mt = 0; mt < 2; ++mt)
                #pragma unroll
                for (int r = 0; r < 4; ++r) {
                    const long sg = base + mh * 32 + mt * 16 + q * 4 + r;
                    if (sg < (long)n) out[sg * 3 + ln] = acc3[mt][r] + b3v;
                }
        }
    }
}

extern "C" void kernel_launch(void* const* d_in, const int* in_sizes, int n_in,
                              void* d_out, int out_size, void* d_ws, size_t ws_size,
                              hipStream_t stream) {
    const float* x      = (const float*)d_in[0];
    const float* tables = (const float*)d_in[1];
    const float* W1     = (const float*)d_in[2];
    const float* b1v    = (const float*)d_in[3];
    const float* W2     = (const float*)d_in[4];
    const float* b2v    = (const float*)d_in[5];
    const float* W3     = (const float*)d_in[6];
    const float* b3v    = (const float*)d_in[7];
    float* out = (float*)d_out;
    unsigned short* wsu = (unsigned short*)d_ws;

    const int n = in_sizes[0] / 2;   // B

    // Replicate numpy's RES computation on the host (glibc libm, float64).
    ResArr ra;
    const double bb = exp((log(512.0) - log(16.0)) / 15.0);
    for (int k = 0; k < 16; ++k) ra.r[k] = (float)floor(16.0 * pow(bb, (double)k));

    // Prepass: hi/lo bf16 weight split into workspace (stream-ordered).
    hipLaunchKernelGGL(split_weights, dim3(8), dim3(256), 0, stream, W1, W2, W3, wsu);

    const size_t need = (size_t)WS_USHORTS * 2 + (size_t)n * 128;
    if (ws_size >= need) {
        // Split path: encode -> feat in ws, then MFMA mlp.
        unsigned short* featp = wsu + WS_USHORTS;
        dim3 gE((n + 255) / 256), bE(256);
        hipLaunchKernelGGL(mh_encode, gE, bE, 0, stream, x, tables, featp, ra, n);
        dim3 gM((n + 63) / 64), bM(64);
        hipLaunchKernelGGL(mh_mlp, gM, bM, 0, stream, featp, wsu, b1v, b2v, b3v, out, n);
    } else {
        // Fallback: R8 fused kernel.
        dim3 grid((n + 63) / 64), block(64);
        hipLaunchKernelGGL(mh_mfma, grid, block, 0, stream,
                           x, tables, wsu, b1v, b2v, b3v, out, ra, n);
    }
}

// Round 4
// 282.303 us; speedup vs baseline: 1.4020x; 1.4020x over previous
//
#include <hip/hip_runtime.h>
#include <hip/hip_bf16.h>
#include <math.h>

// MultiHash R10: revert to the R8 fused structure (R9's two-kernel split
// spilled ~220MB/dispatch of scratch at (64,4) and paid a 256MB feat
// round-trip — both visible in FETCH/WRITE). On top of R8, attack the
// measured bottleneck (all pipes <25% busy -> gather-latency-bound):
//  - PAIR-LOAD trick: i10 == i00^1 and i11 == i01^1 exactly when ux is
//    even ((ux+1)=ux|1 and the hash XOR preserves bit0). The aligned
//    float4 pair containing entry i00 also holds t10 for even-ux lanes.
//    Load pair(i00)+pair(i01) always (2x16B), plus 2 predicated float2
//    loads only for odd-ux lanes: avg 3 transactions/level instead of 4
//    (-25% L1 gather pressure).
//  - unroll 8 (was 4) on the level loop: level addresses are independent,
//    deeper unroll doubles loads in flight, halves latency groups.
// Unchanged from R8 (all validated): fused single-wave block, LDS aliasing
// with a1[2][2] preload (LDS 10240 B), __launch_bounds__(64,3) (4-wave cap
// spills - twice confirmed), weight-split prepass into d_ws, split-bf16
// MFMA MLP, fragment layouts, epilogues. absmax 1.49e-8 vs 8.9e-8.

#define TBL_MASK 16383u
#define PRIME1   2654435761u

typedef __attribute__((ext_vector_type(8))) short short8;
typedef __attribute__((ext_vector_type(4))) float f32x4;
typedef __attribute__((ext_vector_type(4))) unsigned int uint4v;

struct ResArr { float r[16]; };

__device__ __forceinline__ unsigned short bf16rn(float f) {
    __hip_bfloat16 h = __float2bfloat16(f);   // RNE
    return __builtin_bit_cast(unsigned short, h);
}
__device__ __forceinline__ float bf16tof(unsigned short u) {
    unsigned int xx = ((unsigned int)u) << 16;
    return __builtin_bit_cast(float, xx);
}
__device__ __forceinline__ short8 ld8(const unsigned short* p) {
    return __builtin_bit_cast(short8, *(const uint4v*)p);
}

#define MFMA(a, b, c) __builtin_amdgcn_mfma_f32_16x16x32_bf16((a), (b), (c), 0, 0, 0)

// ---- workspace layout (ushort offsets), 16B-aligned blocks ----
#define W1H_OFF 0        // [64][32]
#define W1L_OFF 2048
#define W2H_OFF 4096     // [64][64]
#define W2L_OFF 8192
#define W3H_OFF 12288    // [16][64], rows 3..15 zero
#define W3L_OFF 13312
#define WS_USHORTS 14336 // 28672 B

__global__ __launch_bounds__(256) void split_weights(
    const float* __restrict__ W1, const float* __restrict__ W2,
    const float* __restrict__ W3, unsigned short* __restrict__ ws)
{
    const int t = blockIdx.x * blockDim.x + threadIdx.x;
    const int stride = gridDim.x * blockDim.x;
    for (int i = t; i < 2048; i += stride) {
        const float v = W1[i];
        const unsigned short hb = bf16rn(v);
        ws[W1H_OFF + i] = hb;
        ws[W1L_OFF + i] = bf16rn(v - bf16tof(hb));
    }
    for (int i = t; i < 4096; i += stride) {
        const float v = W2[i];
        const unsigned short hb = bf16rn(v);
        ws[W2H_OFF + i] = hb;
        ws[W2L_OFF + i] = bf16rn(v - bf16tof(hb));
    }
    for (int i = t; i < 1024; i += stride) {
        const float v = (i < 192) ? W3[i] : 0.0f;   // W3 is [3][64]; pad to 16 rows
        const unsigned short hb = bf16rn(v);
        ws[W3H_OFF + i] = hb;
        ws[W3L_OFF + i] = bf16rn(v - bf16tof(hb));
    }
}

__global__ __launch_bounds__(64, 3) void mh_mfma(
    const float* __restrict__ x,
    const float* __restrict__ tables,
    const unsigned short* __restrict__ wsw,
    const float* __restrict__ b1,
    const float* __restrict__ b2,
    const float* __restrict__ b3,
    float* __restrict__ out,
    ResArr res, int n)
{
    // One 10240 B region, two phases:
    //   phase F (encoding + layer-1 A-frag preload): sFH [64][40], sFL [64][40]
    //   phase A (h1/h2 staging):                     sAH [32][72], sAL [32][72]
    __shared__ __align__(16) unsigned short smem[5120];
    unsigned short* const sFH = smem;          // 2560 ushorts
    unsigned short* const sFL = smem + 2560;   // 2560 ushorts
    unsigned short* const sAH = smem;          // 2304 ushorts (aliases sFH)
    unsigned short* const sAL = smem + 2304;   // 2304 ushorts (aliases sFH/sFL)

    const int L  = threadIdx.x;
    const int ln = L & 15;
    const int q  = L >> 4;
    const long base = (long)blockIdx.x * 64;
    long s = base + L;
    if (s >= (long)n) s = (long)n - 1;   // clamp loads; stores predicated below

    const float2 xv = reinterpret_cast<const float2*>(x)[s];
    const float2* __restrict__ tbl2 = reinterpret_cast<const float2*>(tables);

    // ---- encoding: same math as R1/R6 (validated), pair-load gathers ----
    #pragma unroll 8
    for (int l = 0; l < 16; ++l) {
        const float r  = res.r[l];
        const float sx = xv.x * r;
        const float sy = xv.y * r;
        const float gx = floorf(sx);
        const float gy = floorf(sy);
        const unsigned ux = (unsigned)(int)gx;
        const unsigned uy = (unsigned)(int)gy;
        const unsigned hy0 = uy * PRIME1;
        const unsigned hy1 = hy0 + PRIME1;
        const unsigned i00 = ( ux ^ hy0) & TBL_MASK;
        const unsigned i01 = ( ux ^ hy1) & TBL_MASK;
        const float2* tl = tbl2 + (l << 14);
        const float4* tp = (const float4*)tl;
        // Aligned pair loads: entry i00 lives in pair i00>>1; for even ux the
        // other half of the same pair IS t10 (i10 = i00^1). Same for i01/i11.
        const float4 p0 = tp[i00 >> 1];
        const float4 p1 = tp[i01 >> 1];
        const bool b0 = (i00 & 1u) != 0u;
        const bool b1 = (i01 & 1u) != 0u;
        float2 t00, t10, t01, t11;
        t00.x = b0 ? p0.z : p0.x;  t00.y = b0 ? p0.w : p0.y;
        t10.x = b0 ? p0.x : p0.z;  t10.y = b0 ? p0.y : p0.w;   // valid iff ux even
        t01.x = b1 ? p1.z : p1.x;  t01.y = b1 ? p1.w : p1.y;
        t11.x = b1 ? p1.x : p1.z;  t11.y = b1 ? p1.y : p1.w;   // valid iff ux even
        if (ux & 1u) {   // odd ux: i10/i11 not pair-adjacent -> direct loads
            const unsigned i10 = ((ux + 1u) ^ hy0) & TBL_MASK;
            const unsigned i11 = ((ux + 1u) ^ hy1) & TBL_MASK;
            t10 = tl[i10];
            t11 = tl[i11];
        }
        const float wx0 = 1.0f - fabsf(sx - gx);
        const float wx1 = 1.0f - fabsf(sx - (gx + 1.0f));
        const float wy0 = 1.0f - fabsf(sy - gy);
        const float wy1 = 1.0f - fabsf(sy - (gy + 1.0f));
        const float w00 = wx0 * wy0;
        const float w10 = wx1 * wy0;
        const float w01 = wx0 * wy1;
        const float w11 = wx1 * wy1;
        const float f0 = fmaf(w00, t00.x, fmaf(w10, t10.x, fmaf(w01, t01.x, w11 * t11.x)));
        const float f1 = fmaf(w00, t00.y, fmaf(w10, t10.y, fmaf(w01, t01.y, w11 * t11.y)));
        const unsigned short h0 = bf16rn(f0);
        const unsigned short h1e = bf16rn(f1);
        const unsigned short l0 = bf16rn(f0 - bf16tof(h0));
        const unsigned short l1 = bf16rn(f1 - bf16tof(h1e));
        *(unsigned int*)&sFH[L * 40 + 2 * l] = (unsigned)h0 | ((unsigned)h1e << 16);
        *(unsigned int*)&sFL[L * 40 + 2 * l] = (unsigned)l0 | ((unsigned)l1 << 16);
    }

    // ---- preload ALL layer-1 A-fragments (both halves) while sF is live ----
    // After this, sF is dead and the sA writes below may alias it.
    short8 a1h[2][2], a1l[2][2];
    #pragma unroll
    for (int mh = 0; mh < 2; ++mh)
        #pragma unroll
        for (int mt = 0; mt < 2; ++mt) {
            const int row = mh * 32 + mt * 16 + ln;
            a1h[mh][mt] = ld8(&sFH[row * 40 + q * 8]);
            a1l[mh][mt] = ld8(&sFL[row * 40 + q * 8]);
        }

    // biases (per-lane by output column)
    float b1v[4], b2v[4];
    #pragma unroll
    for (int nt = 0; nt < 4; ++nt) { b1v[nt] = b1[nt * 16 + ln]; b2v[nt] = b2[nt * 16 + ln]; }
    const float b3v = (ln < 3) ? b3[ln] : 0.0f;

    const f32x4 zero4 = {0.0f, 0.0f, 0.0f, 0.0f};

    for (int mh = 0; mh < 2; ++mh) {          // 32-sample halves
        // ---------------- layer 1 ----------------
        f32x4 acc1[2][4];
        #pragma unroll
        for (int mt = 0; mt < 2; ++mt)
            #pragma unroll
            for (int nt = 0; nt < 4; ++nt) acc1[mt][nt] = zero4;

        #pragma unroll
        for (int nt = 0; nt < 4; ++nt) {
            const short8 bh = ld8(&wsw[W1H_OFF + (nt * 16 + ln) * 32 + q * 8]);
            const short8 bl = ld8(&wsw[W1L_OFF + (nt * 16 + ln) * 32 + q * 8]);
            #pragma unroll
            for (int mt = 0; mt < 2; ++mt) {
                f32x4 a = acc1[mt][nt];
                a = MFMA(a1l[mh][mt], bh, a);
                a = MFMA(a1h[mh][mt], bl, a);
                a = MFMA(a1h[mh][mt], bh, a);
                acc1[mt][nt] = a;
            }
        }
        // epilogue: bias + relu + split -> sAH/sAL rows 0..31 (aliases sF;
        // safe: all layer-1 A-frags preloaded, same-wave DS ops are in-order)
        #pragma unroll
        for (int mt = 0; mt < 2; ++mt)
            #pragma unroll
            for (int nt = 0; nt < 4; ++nt) {
                const int col = nt * 16 + ln;
                #pragma unroll
                for (int r = 0; r < 4; ++r) {
                    float v = fmaxf(acc1[mt][nt][r] + b1v[nt], 0.0f);
                    const unsigned short hb = bf16rn(v);
                    const unsigned short lb = bf16rn(v - bf16tof(hb));
                    const int rl = mt * 16 + q * 4 + r;
                    sAH[rl * 72 + col] = hb;
                    sAL[rl * 72 + col] = lb;
                }
            }

        // ---------------- layer 2 ----------------
        short8 a2h[2][2], a2l[2][2];
        #pragma unroll
        for (int mt = 0; mt < 2; ++mt)
            #pragma unroll
            for (int ks = 0; ks < 2; ++ks) {
                const int row = mt * 16 + ln;
                a2h[mt][ks] = ld8(&sAH[row * 72 + ks * 32 + q * 8]);
                a2l[mt][ks] = ld8(&sAL[row * 72 + ks * 32 + q * 8]);
            }
        f32x4 acc2[2][4];
        #pragma unroll
        for (int mt = 0; mt < 2; ++mt)
            #pragma unroll
            for (int nt = 0; nt < 4; ++nt) acc2[mt][nt] = zero4;

        #pragma unroll
        for (int nt = 0; nt < 4; ++nt)
            #pragma unroll
            for (int ks = 0; ks < 2; ++ks) {
                const short8 bh = ld8(&wsw[W2H_OFF + (nt * 16 + ln) * 64 + ks * 32 + q * 8]);
                const short8 bl = ld8(&wsw[W2L_OFF + (nt * 16 + ln) * 64 + ks * 32 + q * 8]);
                #pragma unroll
                for (int mt = 0; mt < 2; ++mt) {
                    f32x4 a = acc2[mt][nt];
                    a = MFMA(a2l[mt][ks], bh, a);
                    a = MFMA(a2h[mt][ks], bl, a);
                    a = MFMA(a2h[mt][ks], bh, a);
                    acc2[mt][nt] = a;
                }
            }
        // epilogue: bias + relu + split -> overwrite sAH/sAL (same-wave DS
        // ops retire in order; A-frags above were already read)
        #pragma unroll
        for (int mt = 0; mt < 2; ++mt)
            #pragma unroll
            for (int nt = 0; nt < 4; ++nt) {
                const int col = nt * 16 + ln;
                #pragma unroll
                for (int r = 0; r < 4; ++r) {
                    float v = fmaxf(acc2[mt][nt][r] + b2v[nt], 0.0f);
                    const unsigned short hb = bf16rn(v);
                    const unsigned short lb = bf16rn(v - bf16tof(hb));
                    const int rl = mt * 16 + q * 4 + r;
                    sAH[rl * 72 + col] = hb;
                    sAL[rl * 72 + col] = lb;
                }
            }

        // ---------------- layer 3 ----------------
        short8 a3h[2][2], a3l[2][2];
        #pragma unroll
        for (int mt = 0; mt < 2; ++mt)
            #pragma unroll
            for (int ks = 0; ks < 2; ++ks) {
                const int row = mt * 16 + ln;
                a3h[mt][ks] = ld8(&sAH[row * 72 + ks * 32 + q * 8]);
                a3l[mt][ks] = ld8(&sAL[row * 72 + ks * 32 + q * 8]);
            }
        f32x4 acc3[2] = {zero4, zero4};
        #pragma unroll
        for (int ks = 0; ks < 2; ++ks) {
            // W3 pre-padded to 16 rows (3..15 zero) -> no divergent mask
            const short8 bh = ld8(&wsw[W3H_OFF + ln * 64 + ks * 32 + q * 8]);
            const short8 bl = ld8(&wsw[W3L_OFF + ln * 64 + ks * 32 + q * 8]);
            #pragma unroll
            for (int mt = 0; mt < 2; ++mt) {
                f32x4 a = acc3[mt];
                a = MFMA(a3l[mt][ks], bh, a);
                a = MFMA(a3h[mt][ks], bl, a);
                a = MFMA(a3h[mt][ks], bh, a);
                acc3[mt] = a;
            }
        }
        // store: C col = ln (channel, <3), rows = samples
        if (ln < 3) {
            #pragma unroll
            for (int mt = 0; mt < 2; ++mt)
                #pragma unroll
                for (int r = 0; r < 4; ++r) {
                    const long sg = base + mh * 32 + mt * 16 + q * 4 + r;
                    if (sg < (long)n) out[sg * 3 + ln] = acc3[mt][r] + b3v;
                }
        }
    }
}

extern "C" void kernel_launch(void* const* d_in, const int* in_sizes, int n_in,
                              void* d_out, int out_size, void* d_ws, size_t ws_size,
                              hipStream_t stream) {
    const float* x      = (const float*)d_in[0];
    const float* tables = (const float*)d_in[1];
    const float* W1     = (const float*)d_in[2];
    const float* b1v    = (const float*)d_in[3];
    const float* W2     = (const float*)d_in[4];
    const float* b2v    = (const float*)d_in[5];
    const float* W3     = (const float*)d_in[6];
    const float* b3v    = (const float*)d_in[7];
    float* out = (float*)d_out;
    unsigned short* wsu = (unsigned short*)d_ws;

    const int n = in_sizes[0] / 2;   // B

    // Replicate numpy's RES computation on the host (glibc libm, float64).
    ResArr ra;
    const double bb = exp((log(512.0) - log(16.0)) / 15.0);
    for (int k = 0; k < 16; ++k) ra.r[k] = (float)floor(16.0 * pow(bb, (double)k));

    // Prepass: hi/lo bf16 weight split into workspace (stream-ordered).
    hipLaunchKernelGGL(split_weights, dim3(8), dim3(256), 0, stream, W1, W2, W3, wsu);

    dim3 grid((n + 63) / 64), block(64);
    hipLaunchKernelGGL(mh_mfma, grid, block, 0, stream,
                       x, tables, wsu, b1v, b2v, b3v, out, ra, n);
}